// Round 4
// baseline (1455.489 us; speedup 1.0000x reference)
//
#include <hip/hip_runtime.h>
#include <math.h>

// ---- problem constants ----
constexpr int B_ = 64, L_ = 256, T_ = 32, E_ = 384, H_ = 6;
constexpr int DI_ = 768, DS_ = 16, DC_ = 4, DR_ = 24;
constexpr int HID_ = 1536, V_ = 97, ND_ = 12;
constexpr float EPS_ = 1e-5f;
constexpr int HD_ = 64;

typedef unsigned short ushort_t;
typedef __attribute__((ext_vector_type(8))) short  short8;
typedef __attribute__((ext_vector_type(4))) float  floatx4;
typedef __attribute__((ext_vector_type(8))) unsigned short ushort8v;

__device__ __forceinline__ float siluf(float x) { return x / (1.f + expf(-x)); }
__device__ __forceinline__ float softplusf(float x) {
    return fmaxf(x, 0.f) + log1pf(expf(-fabsf(x)));
}
__device__ __forceinline__ ushort_t f2bf(float f) {
    unsigned int u = __float_as_uint(f);
    u += 0x7fffu + ((u >> 16) & 1u);
    return (ushort_t)(u >> 16);
}
__device__ __forceinline__ float bf2f(ushort_t u) {
    return __uint_as_float(((unsigned int)u) << 16);
}
__device__ __forceinline__ void unpack2(unsigned int w, float& lo, float& hi) {
    lo = __uint_as_float(w << 16);
    hi = __uint_as_float(w & 0xffff0000u);
}
// async global->LDS, 16B/lane; dest = wave-uniform base + lane*16
__device__ __forceinline__ void gl_lds16(const ushort_t* g, ushort_t* l) {
    __builtin_amdgcn_global_load_lds(
        (const __attribute__((address_space(1))) unsigned int*)g,
        (__attribute__((address_space(3))) unsigned int*)l, 16, 0, 0);
}

// ---------------------------------------------------------------------------
// fp32 -> bf16 converters
// ---------------------------------------------------------------------------
__global__ __launch_bounds__(256) void cvt_bf16_kernel(
    const float* __restrict__ src, ushort_t* __restrict__ dst, long n4) {
    long i = (long)blockIdx.x * 256 + threadIdx.x;
    if (i >= n4) return;
    float4 v = ((const float4*)src)[i];
    __attribute__((ext_vector_type(4))) unsigned short o;
    o[0] = f2bf(v.x); o[1] = f2bf(v.y); o[2] = f2bf(v.z); o[3] = f2bf(v.w);
    *(__attribute__((ext_vector_type(4))) unsigned short*)(dst + i * 4) = o;
}

__global__ __launch_bounds__(256) void cvt_pad_kernel(
    const float* __restrict__ src, ushort_t* __restrict__ dst,
    int sr, int sc, int dr, int dc, int layers) {
    long total = (long)layers * dr * dc;
    long idx = (long)blockIdx.x * 256 + threadIdx.x;
    if (idx >= total) return;
    int l = (int)(idx / ((long)dr * dc));
    int rem = (int)(idx % ((long)dr * dc));
    int r = rem / dc, c = rem % dc;
    float v = (r < sr && c < sc) ? src[((long)l * sr + r) * sc + c] : 0.f;
    dst[idx] = f2bf(v);
}

// ---------------------------------------------------------------------------
// 128x128-tile bf16 MFMA GEMM (m93/m97 structure).
// Requires M%128==0, N%128==0, K%64==0.
// ACT: 0 none, 1 relu, 3 silu-if-gn>=768 (fused mamba z-gate).
// OBF: 1 bf16 out, 0 fp32 out.
// ---------------------------------------------------------------------------
template <int ACT, int OBF>
__global__ __launch_bounds__(256) void gemm128(
    const ushort_t* __restrict__ A, int lda,
    const ushort_t* __restrict__ W,
    const float* __restrict__ bias,
    const float* __restrict__ addin,
    void* __restrict__ Cv,
    int M, int N, int K, int ldc) {
    __shared__ ushort_t As[128 * 64];
    __shared__ ushort_t Bs[128 * 64];

    const int tid = threadIdx.x;
    const int wv = tid >> 6, ln = tid & 63;
    const int bm = blockIdx.x * 128, bn = blockIdx.y * 128;
    const int lm = ln & 15, quad = ln >> 4;
    const int wm = (wv & 1) * 64, wn = (wv >> 1) * 64;
    const int r8 = ln >> 3, c8 = ln & 7;

    floatx4 acc[4][4] = {};

    for (int k0 = 0; k0 < K; k0 += 64) {
#pragma unroll
        for (int j = 0; j < 4; ++j) {
            int row = wv * 32 + j * 8 + r8;
            int cg = c8 ^ (row & 7);
            gl_lds16(A + (size_t)(bm + row) * lda + k0 + cg * 8,
                     &As[(wv * 32 + j * 8) * 64]);
        }
#pragma unroll
        for (int j = 0; j < 4; ++j) {
            int row = wv * 32 + j * 8 + r8;
            int cg = c8 ^ (row & 7);
            gl_lds16(W + (size_t)(bn + row) * K + k0 + cg * 8,
                     &Bs[(wv * 32 + j * 8) * 64]);
        }
        __syncthreads();
#pragma unroll
        for (int ks2 = 0; ks2 < 2; ++ks2) {
            const int pc = ((quad + ks2 * 4) ^ (lm & 7)) * 8;
            short8 a[4], b[4];
#pragma unroll
            for (int i = 0; i < 4; ++i)
                a[i] = *(const short8*)&As[(wm + i * 16 + lm) * 64 + pc];
#pragma unroll
            for (int i = 0; i < 4; ++i)
                b[i] = *(const short8*)&Bs[(wn + i * 16 + lm) * 64 + pc];
#pragma unroll
            for (int i = 0; i < 4; ++i)
#pragma unroll
                for (int j = 0; j < 4; ++j)
                    acc[i][j] = __builtin_amdgcn_mfma_f32_16x16x32_bf16(
                        a[i], b[j], acc[i][j], 0, 0, 0);
        }
        __syncthreads();
    }

    // C/D layout: col = lane&15, row = quad*4 + reg  [m89-verified]
#pragma unroll
    for (int sm = 0; sm < 4; ++sm) {
#pragma unroll
        for (int sn = 0; sn < 4; ++sn) {
            const int gn = bn + wn + sn * 16 + lm;
#pragma unroll
            for (int r = 0; r < 4; ++r) {
                const int gm = bm + wm + sm * 16 + quad * 4 + r;
                float v = acc[sm][sn][r];
                if (bias) v += bias[gn];
                if (ACT == 1) v = fmaxf(v, 0.f);
                if (ACT == 3 && gn >= 768) v = siluf(v);
                if (addin) v += addin[(size_t)gm * ldc + gn];
                if (OBF)
                    ((ushort_t*)Cv)[(size_t)gm * ldc + gn] = f2bf(v);
                else
                    ((float*)Cv)[(size_t)gm * ldc + gn] = v;
            }
        }
    }
}

// ---------------------------------------------------------------------------
// 64x64-tile GEMM for small-N shapes (N padded to Nz, zero-filled).
// ---------------------------------------------------------------------------
template <int ACT, int OBF>
__global__ __launch_bounds__(256) void gemm_bf16(
    const ushort_t* __restrict__ A, int lda,
    const ushort_t* __restrict__ W,
    const float* __restrict__ bias,
    const float* __restrict__ addin,
    void* __restrict__ Cv,
    int M, int N, int K, int Nz, int ldc) {
    __shared__ ushort_t As[64 * 64];
    __shared__ ushort_t Bs[64 * 64];

    const int tid = threadIdx.x;
    const int wv = tid >> 6, ln = tid & 63;
    const int bm = blockIdx.x * 64, bn = blockIdx.y * 64;
    const int lm = ln & 15, quad = ln >> 4;
    const int wm = (wv & 1) * 32, wn = (wv >> 1) * 32;
    const int r8 = ln >> 3, c8 = ln & 7;

    floatx4 acc[2][2] = {};

    for (int k0 = 0; k0 < K; k0 += 64) {
#pragma unroll
        for (int j = 0; j < 2; ++j) {
            int row = wv * 16 + j * 8 + r8;
            int cg = c8 ^ (row & 7);
            gl_lds16(A + (size_t)(bm + row) * lda + k0 + cg * 8,
                     &As[(wv * 16 + j * 8) * 64]);
        }
#pragma unroll
        for (int j = 0; j < 2; ++j) {
            int row = wv * 16 + j * 8 + r8;
            int cg = c8 ^ (row & 7);
            gl_lds16(W + (size_t)(bn + row) * K + k0 + cg * 8,
                     &Bs[(wv * 16 + j * 8) * 64]);
        }
        __syncthreads();
#pragma unroll
        for (int ks2 = 0; ks2 < 2; ++ks2) {
            int pc = ((quad + ks2 * 4) ^ (lm & 7)) * 8;
            short8 a0 = *(const short8*)&As[(wm + lm) * 64 + pc];
            short8 a1 = *(const short8*)&As[(wm + 16 + lm) * 64 + pc];
            short8 b0 = *(const short8*)&Bs[(wn + lm) * 64 + pc];
            short8 b1 = *(const short8*)&Bs[(wn + 16 + lm) * 64 + pc];
            acc[0][0] = __builtin_amdgcn_mfma_f32_16x16x32_bf16(a0, b0, acc[0][0], 0, 0, 0);
            acc[0][1] = __builtin_amdgcn_mfma_f32_16x16x32_bf16(a0, b1, acc[0][1], 0, 0, 0);
            acc[1][0] = __builtin_amdgcn_mfma_f32_16x16x32_bf16(a1, b0, acc[1][0], 0, 0, 0);
            acc[1][1] = __builtin_amdgcn_mfma_f32_16x16x32_bf16(a1, b1, acc[1][1], 0, 0, 0);
        }
        __syncthreads();
    }

#pragma unroll
    for (int sm = 0; sm < 2; ++sm) {
#pragma unroll
        for (int sn = 0; sn < 2; ++sn) {
            const int gn = bn + wn + sn * 16 + lm;
            if (gn >= Nz) continue;
#pragma unroll
            for (int r = 0; r < 4; ++r) {
                const int gm = bm + wm + sm * 16 + quad * 4 + r;
                float v;
                if (gn < N) {
                    v = acc[sm][sn][r];
                    if (bias) v += bias[gn];
                    if (ACT == 1) v = fmaxf(v, 0.f);
                    if (addin) v += addin[(size_t)gm * ldc + gn];
                } else {
                    v = 0.f;
                }
                if (OBF)
                    ((ushort_t*)Cv)[(size_t)gm * ldc + gn] = f2bf(v);
                else
                    ((float*)Cv)[(size_t)gm * ldc + gn] = v;
            }
        }
    }
}

// ---------------------------------------------------------------------------
__global__ void init_kernel(const float* __restrict__ qe,
                            const float* __restrict__ pos,
                            float* __restrict__ houtf,
                            float* __restrict__ residual) {
    long idx = (long)blockIdx.x * 256 + threadIdx.x;
    if (idx >= (long)B_ * T_ * E_) return;
    int te = (int)(idx % ((long)T_ * E_));
    houtf[idx] = qe[te] + pos[te];
    residual[idx] = 0.f;
}

// wave-per-row: residual += hin; hout = bf16(rmsnorm(residual)*w). grid=M/4.
__global__ __launch_bounds__(256) void add_rmsnorm_kernel(
    const float* __restrict__ hin, float* __restrict__ residual,
    ushort_t* __restrict__ hout, const float* __restrict__ w) {
    const int row = blockIdx.x * 4 + (threadIdx.x >> 6);
    const int lane = threadIdx.x & 63;
    const long base = (long)row * E_;
    float x[6], s = 0.f;
#pragma unroll
    for (int j = 0; j < 6; ++j) {
        long idx = base + lane + j * 64;
        x[j] = hin[idx] + residual[idx];
        residual[idx] = x[j];
        s += x[j] * x[j];
    }
#pragma unroll
    for (int off = 1; off < 64; off <<= 1) s += __shfl_xor(s, off);
    float sc = rsqrtf(s / E_ + EPS_);
#pragma unroll
    for (int j = 0; j < 6; ++j)
        hout[base + lane + j * 64] = f2bf(x[j] * sc * w[lane + j * 64]);
}

// wave-per-row layernorm, fp32 in -> bf16 out. grid=M/4.
__global__ __launch_bounds__(256) void layernorm_kernel(
    const float* __restrict__ xin, const float* __restrict__ w,
    const float* __restrict__ b, ushort_t* __restrict__ out) {
    const int row = blockIdx.x * 4 + (threadIdx.x >> 6);
    const int lane = threadIdx.x & 63;
    const long base = (long)row * E_;
    float x[6], s = 0.f, s2 = 0.f;
#pragma unroll
    for (int j = 0; j < 6; ++j) {
        x[j] = xin[base + lane + j * 64];
        s += x[j];
        s2 += x[j] * x[j];
    }
#pragma unroll
    for (int off = 1; off < 64; off <<= 1) {
        s += __shfl_xor(s, off);
        s2 += __shfl_xor(s2, off);
    }
    float mu = s / E_;
    float var = s2 / E_ - mu * mu;
    float sc = rsqrtf(var + EPS_);
#pragma unroll
    for (int j = 0; j < 6; ++j) {
        int c = lane + j * 64;
        out[base + c] = f2bf((x[j] - mu) * sc * w[c] + b[c]);
    }
}

// ---------------------------------------------------------------------------
// depthwise causal conv (DC=4) + bias + SiLU over xm half of xz
// ---------------------------------------------------------------------------
__global__ __launch_bounds__(256) void conv_silu_kernel(
    const ushort_t* __restrict__ xz, const float* __restrict__ cw,
    const float* __restrict__ cb, ushort_t* __restrict__ xc) {
    int idx = blockIdx.x * 256 + threadIdx.x;  // over B*T*(DI/8)
    if (idx >= B_ * T_ * (DI_ / 8)) return;
    int dc = idx % (DI_ / 8);
    int t = (idx / (DI_ / 8)) % T_;
    int b = idx / ((DI_ / 8) * T_);
    int d0 = dc * 8;

    float4 cwj[8];
#pragma unroll
    for (int j = 0; j < 8; ++j) cwj[j] = *(const float4*)&cw[(d0 + j) * 4];
    float acc[8];
#pragma unroll
    for (int j = 0; j < 8; ++j) acc[j] = cb[d0 + j];

#pragma unroll
    for (int k = 0; k < DC_; ++k) {
        int tt = t + k - (DC_ - 1);
        if (tt < 0) continue;
        uint4 u = *(const uint4*)(xz + (size_t)(b * T_ + tt) * (2 * DI_) + d0);
        float x[8];
        unpack2(u.x, x[0], x[1]); unpack2(u.y, x[2], x[3]);
        unpack2(u.z, x[4], x[5]); unpack2(u.w, x[6], x[7]);
#pragma unroll
        for (int j = 0; j < 8; ++j) {
            float wv = (k == 0) ? cwj[j].x : (k == 1) ? cwj[j].y
                     : (k == 2) ? cwj[j].z : cwj[j].w;
            acc[j] += wv * x[j];
        }
    }
    ushort8v o;
#pragma unroll
    for (int j = 0; j < 8; ++j) o[j] = f2bf(siluf(acc[j]));
    *(ushort8v*)(xc + (size_t)(b * T_ + t) * DI_ + d0) = o;
}

// ---------------------------------------------------------------------------
// selective scan with fused dt-projection (fp32). grid (DI/256, B).
// z gate is pre-silu'd by gemm128<ACT=3> into xz[..., 768+d].
// ---------------------------------------------------------------------------
__global__ __launch_bounds__(256) void mamba_scan_kernel(
    const ushort_t* __restrict__ dbl,   // B*T*64 bf16 (dt-in 0..23, B 24..39, C 40..55)
    const ushort_t* __restrict__ xc,    // B*T*DI bf16
    const ushort_t* __restrict__ xz,    // B*T*1536 bf16 (silu(z) at +768)
    const float* __restrict__ dtw,      // DI*DR fp32 (layer slice)
    const float* __restrict__ dtbias,   // DI fp32
    const float* __restrict__ Alog,     // DI*DS fp32
    const float* __restrict__ Dp,       // DI fp32
    ushort_t* __restrict__ y) {
    const int d = blockIdx.x * 256 + threadIdx.x;
    const int b = blockIdx.y;
    __shared__ float Db[T_][DR_];
    __shared__ float Bs[T_][DS_];
    __shared__ float Cs[T_][DS_];
    for (int i = threadIdx.x; i < T_ * 56; i += 256) {
        int t = i / 56, c = i % 56;
        float v = bf2f(dbl[(size_t)(b * T_ + t) * 64 + c]);
        if (c < DR_) Db[t][c] = v;
        else if (c < DR_ + DS_) Bs[t][c - DR_] = v;
        else Cs[t][c - DR_ - DS_] = v;
    }
    __syncthreads();

    float wr[DR_];
#pragma unroll
    for (int r = 0; r < DR_; ++r) wr[r] = dtw[(size_t)d * DR_ + r];
    const float dtb_v = dtbias[d];

    float Aa[DS_];
#pragma unroll
    for (int s = 0; s < DS_; ++s) Aa[s] = -expf(Alog[(size_t)d * DS_ + s]);
    float h[DS_] = {};
    const float Dv = Dp[d];

    for (int t = 0; t < T_; ++t) {
        float dtv = dtb_v;
#pragma unroll
        for (int r = 0; r < DR_; ++r) dtv += Db[t][r] * wr[r];
        dtv = softplusf(dtv);

        size_t idx = (size_t)(b * T_ + t) * DI_ + d;
        float xcv = bf2f(xc[idx]);
        float acc = 0.f;
#pragma unroll
        for (int s = 0; s < DS_; ++s) {
            h[s] = expf(dtv * Aa[s]) * h[s] + dtv * Bs[t][s] * xcv;
            acc += h[s] * Cs[t][s];
        }
        float zv = bf2f(xz[(size_t)(b * T_ + t) * (2 * DI_) + DI_ + d]);
        y[idx] = f2bf((acc + Dv * xcv) * zv);
    }
}

// ---------------------------------------------------------------------------
// cross-attention: one block per (b,h). (unchanged from round 3)
// ---------------------------------------------------------------------------
__global__ __launch_bounds__(256) void attn_kernel(
    const ushort_t* __restrict__ qh,
    const ushort_t* __restrict__ kh,
    const ushort_t* __restrict__ vh,
    ushort_t* __restrict__ ctx) {
    const int h = blockIdx.x % H_;
    const int b = blockIdx.x / H_;
    const int tid = threadIdx.x;

    __shared__ ushort_t Ks[L_ * HD_];
    __shared__ ushort_t Vs[L_ * HD_];
    __shared__ ushort_t Qs[T_ * HD_];
    __shared__ float Sc[T_ * L_];
    __shared__ float red8[T_][8];
    __shared__ float mx[T_], dn[T_];

    {
        int t = tid >> 3, c = tid & 7;
        *(uint4*)&Qs[t * 64 + c * 8] =
            *(const uint4*)(qh + (size_t)(b * T_ + t) * E_ + h * HD_ + c * 8);
    }
    {
        int s = tid;
        const ushort_t* kr = kh + (size_t)(b * L_ + s) * E_ + h * HD_;
        const ushort_t* vr = vh + (size_t)(b * L_ + s) * E_ + h * HD_;
#pragma unroll
        for (int c = 0; c < 8; ++c) {
            int cp = (c ^ (s & 7)) * 8;
            *(uint4*)&Ks[s * 64 + cp] = *(const uint4*)(kr + c * 8);
            *(uint4*)&Vs[s * 64 + cp] = *(const uint4*)(vr + c * 8);
        }
    }
    __syncthreads();

    {
        int s = tid;
        float kr[64];
#pragma unroll
        for (int c = 0; c < 8; ++c) {
            int cp = (c ^ (s & 7)) * 8;
            uint4 u = *(const uint4*)&Ks[s * 64 + cp];
            unpack2(u.x, kr[c * 8 + 0], kr[c * 8 + 1]);
            unpack2(u.y, kr[c * 8 + 2], kr[c * 8 + 3]);
            unpack2(u.z, kr[c * 8 + 4], kr[c * 8 + 5]);
            unpack2(u.w, kr[c * 8 + 6], kr[c * 8 + 7]);
        }
        for (int t = 0; t < T_; ++t) {
            float d = 0.f;
#pragma unroll
            for (int c = 0; c < 8; ++c) {
                uint4 qu = *(const uint4*)&Qs[t * 64 + c * 8];
                float q0, q1, q2, q3, q4, q5, q6, q7;
                unpack2(qu.x, q0, q1); unpack2(qu.y, q2, q3);
                unpack2(qu.z, q4, q5); unpack2(qu.w, q6, q7);
                d += q0 * kr[c * 8 + 0] + q1 * kr[c * 8 + 1] +
                     q2 * kr[c * 8 + 2] + q3 * kr[c * 8 + 3] +
                     q4 * kr[c * 8 + 4] + q5 * kr[c * 8 + 5] +
                     q6 * kr[c * 8 + 6] + q7 * kr[c * 8 + 7];
            }
            Sc[t * L_ + s] = d * 0.125f;
        }
    }
    __syncthreads();

    {
        int t = tid >> 3, j = tid & 7;
        float m = -1e30f;
        for (int s = j * 32; s < j * 32 + 32; ++s) m = fmaxf(m, Sc[t * L_ + s]);
        red8[t][j] = m;
    }
    __syncthreads();
    if (tid < T_) {
        float m = red8[tid][0];
#pragma unroll
        for (int j = 1; j < 8; ++j) m = fmaxf(m, red8[tid][j]);
        mx[tid] = m;
    }
    __syncthreads();
    {
        int t = tid >> 3, j = tid & 7;
        float m = mx[t], sum = 0.f;
        for (int s = j * 32; s < j * 32 + 32; ++s) {
            float e = expf(Sc[t * L_ + s] - m);
            Sc[t * L_ + s] = e;
            sum += e;
        }
        red8[t][j] = sum;
    }
    __syncthreads();
    if (tid < T_) {
        float s = 0.f;
#pragma unroll
        for (int j = 0; j < 8; ++j) s += red8[tid][j];
        dn[tid] = 1.f / s;
    }
    __syncthreads();

    {
        int t = tid >> 3, c = tid & 7;
        float o[8] = {};
        for (int si = 0; si < L_; ++si) {
            int s = (si + t * 33) & (L_ - 1);
            float p = Sc[t * L_ + s];
            int cp = (c ^ (s & 7)) * 8;
            uint4 u = *(const uint4*)&Vs[s * 64 + cp];
            float v0, v1, v2, v3, v4, v5, v6, v7;
            unpack2(u.x, v0, v1); unpack2(u.y, v2, v3);
            unpack2(u.z, v4, v5); unpack2(u.w, v6, v7);
            o[0] += p * v0; o[1] += p * v1; o[2] += p * v2; o[3] += p * v3;
            o[4] += p * v4; o[5] += p * v5; o[6] += p * v6; o[7] += p * v7;
        }
        float sc = dn[t];
        ushort8v pk;
#pragma unroll
        for (int j = 0; j < 8; ++j) pk[j] = f2bf(o[j] * sc);
        *(ushort8v*)(ctx + (size_t)(b * T_ + t) * E_ + h * HD_ + c * 8) = pk;
    }
}

// ---------------------------------------------------------------------------
static void g128(hipStream_t s, int act, int obf, const ushort_t* A, int lda,
                 const ushort_t* W, const float* bias, const float* addin,
                 void* C, int M, int N, int K, int ldc) {
    dim3 g(M / 128, N / 128), b(256);
    if (obf) {
        switch (act) {
            case 0: gemm128<0, 1><<<g, b, 0, s>>>(A, lda, W, bias, addin, C, M, N, K, ldc); break;
            case 1: gemm128<1, 1><<<g, b, 0, s>>>(A, lda, W, bias, addin, C, M, N, K, ldc); break;
            case 3: gemm128<3, 1><<<g, b, 0, s>>>(A, lda, W, bias, addin, C, M, N, K, ldc); break;
        }
    } else {
        gemm128<0, 0><<<g, b, 0, s>>>(A, lda, W, bias, addin, C, M, N, K, ldc);
    }
}

static void g64(hipStream_t s, int obf, const ushort_t* A, int lda,
                const ushort_t* W, const float* bias, const float* addin,
                void* C, int M, int N, int K, int Nz, int ldc) {
    dim3 g(M / 64, (Nz + 63) / 64), b(256);
    if (obf)
        gemm_bf16<0, 1><<<g, b, 0, s>>>(A, lda, W, bias, addin, C, M, N, K, Nz, ldc);
    else
        gemm_bf16<0, 0><<<g, b, 0, s>>>(A, lda, W, bias, addin, C, M, N, K, Nz, ldc);
}

static void cvt(hipStream_t s, const float* src, ushort_t* dst, long n) {
    long n4 = n / 4;
    cvt_bf16_kernel<<<(int)((n4 + 255) / 256), 256, 0, s>>>(src, dst, n4);
}
static void cvt_pad(hipStream_t s, const float* src, ushort_t* dst,
                    int sr, int sc, int dr, int dc, int layers) {
    long total = (long)layers * dr * dc;
    cvt_pad_kernel<<<(int)((total + 255) / 256), 256, 0, s>>>(src, dst, sr, sc, dr, dc, layers);
}

extern "C" void kernel_launch(void* const* d_in, const int* in_sizes, int n_in,
                              void* d_out, int out_size, void* d_ws, size_t ws_size,
                              hipStream_t stream) {
    const float* enc      = (const float*)d_in[0];
    const float* qe       = (const float*)d_in[1];
    const float* pos      = (const float*)d_in[2];
    const float* m_norm_w = (const float*)d_in[3];
    const float* m_in_w   = (const float*)d_in[4];
    const float* m_conv_w = (const float*)d_in[5];
    const float* m_conv_b = (const float*)d_in[6];
    const float* m_xproj_w= (const float*)d_in[7];
    const float* m_dt_w   = (const float*)d_in[8];
    const float* m_dt_b   = (const float*)d_in[9];
    const float* m_Alog   = (const float*)d_in[10];
    const float* m_D      = (const float*)d_in[11];
    const float* m_out_w  = (const float*)d_in[12];
    const float* rms_w    = (const float*)d_in[13];
    const float* wq = (const float*)d_in[14];
    const float* bq = (const float*)d_in[15];
    const float* wk = (const float*)d_in[16];
    const float* bk = (const float*)d_in[17];
    const float* wv = (const float*)d_in[18];
    const float* bv = (const float*)d_in[19];
    const float* wo = (const float*)d_in[20];
    const float* bo = (const float*)d_in[21];
    const float* ln1_w = (const float*)d_in[22];
    const float* ln1_b = (const float*)d_in[23];
    const float* ffn_w1 = (const float*)d_in[24];
    const float* ffn_b1 = (const float*)d_in[25];
    const float* ffn_w2 = (const float*)d_in[26];
    const float* ffn_b2 = (const float*)d_in[27];
    const float* ln2_w = (const float*)d_in[28];
    const float* ln2_b = (const float*)d_in[29];
    const float* out_w = (const float*)d_in[30];
    const float* out_b = (const float*)d_in[31];

    const long SZ_BTE = (long)B_ * T_ * E_;  // 786432
    float* residual = (float*)d_ws;
    float* houtf    = residual + SZ_BTE;

    ushort_t* u = (ushort_t*)(houtf + SZ_BTE);
    ushort_t* hidden = u;                    // 786,432
    ushort_t* S      = hidden + SZ_BTE;      // union region
    // mamba-phase layout:
    ushort_t* xz  = S;                       // 3,145,728 (z half pre-silu'd)
    ushort_t* xc  = xz + 3145728;            // 1,572,864
    ushort_t* dbl = xc + 1572864;            //   131,072 (2048 x 64 padded)
    ushort_t* yb  = dbl + 131072;            // 1,572,864  (end 6,422,528)
    // attention-phase aliases:
    ushort_t* enc_bf = S;                    // 6,291,456
    ushort_t* qh  = S + 6291456;             //   786,432
    ushort_t* ctx = qh + 786432;             //   786,432
    // ffn alias:
    ushort_t* ffnb = S;                      // 3,145,728
    ushort_t* kh = S + 7995392;              // 6,291,456
    ushort_t* vh = kh + 6291456;             // 6,291,456

    // bf16 weights
    ushort_t* w_in    = vh + 6291456;        // 7,077,888
    ushort_t* w_xproj = w_in + 7077888;      // 12*64*768 (rows 56..63 zero)
    ushort_t* w_out   = w_xproj + 589824;    // 3,538,944
    ushort_t* w_q     = w_out + 3538944;
    ushort_t* w_k     = w_q + 147456;
    ushort_t* w_v     = w_k + 147456;
    ushort_t* w_o     = w_v + 147456;
    ushort_t* w_f1    = w_o + 147456;
    ushort_t* w_f2    = w_f1 + 589824;
    ushort_t* w_lg    = w_f2 + 589824;       // 128*384 (rows 97..127 zero)

    const int M  = B_ * T_;   // 2048
    const int MK = B_ * L_;   // 16384

    // ---- weight conversion (every launch) ----
    cvt(stream, m_in_w,  w_in,  7077888);
    cvt_pad(stream, m_xproj_w, w_xproj, 56, 768, 64, 768, 12);
    cvt(stream, m_out_w, w_out, 3538944);
    cvt(stream, wq, w_q, 147456);
    cvt(stream, wk, w_k, 147456);
    cvt(stream, wv, w_v, 147456);
    cvt(stream, wo, w_o, 147456);
    cvt(stream, ffn_w1, w_f1, 589824);
    cvt(stream, ffn_w2, w_f2, 589824);
    cvt_pad(stream, out_w, w_lg, 97, 384, 128, 384, 1);

    init_kernel<<<(int)((SZ_BTE + 255) / 256), 256, 0, stream>>>(qe, pos, houtf, residual);

    for (int l = 0; l < ND_; ++l) {
        add_rmsnorm_kernel<<<M / 4, 256, 0, stream>>>(houtf, residual, hidden,
                                                      m_norm_w + (long)l * E_);
        // in_proj (128^2, fused silu on z half)
        g128(stream, 3, 1, hidden, E_, w_in + (long)l * 1536 * 384,
             nullptr, nullptr, xz, M, 1536, 384, 1536);
        conv_silu_kernel<<<(M * (DI_ / 8) + 255) / 256, 256, 0, stream>>>(
            xz, m_conv_w + (long)l * DI_ * DC_, m_conv_b + (long)l * DI_, xc);
        g64(stream, 1, xc, DI_, w_xproj + (long)l * 64 * 768,
            nullptr, nullptr, dbl, M, 56, 768, 64, 64);
        mamba_scan_kernel<<<dim3(DI_ / 256, B_), 256, 0, stream>>>(
            dbl, xc, xz,
            m_dt_w + (long)l * DI_ * DR_, m_dt_b + (long)l * DI_,
            m_Alog + (long)l * DI_ * DS_, m_D + (long)l * DI_, yb);
        g64(stream, 0, yb, DI_, w_out + (long)l * 384 * 768,
            nullptr, nullptr, houtf, M, 384, 768, 384, 384);
    }

    add_rmsnorm_kernel<<<M / 4, 256, 0, stream>>>(houtf, residual, hidden, rms_w);

    g64(stream, 1, hidden, E_, w_q, bq, nullptr, qh, M, 384, 384, 384, 384);
    cvt(stream, enc, enc_bf, (long)MK * E_);
    g128(stream, 0, 1, enc_bf, E_, w_k, bk, nullptr, kh, MK, 384, 384, 384);
    g128(stream, 0, 1, enc_bf, E_, w_v, bv, nullptr, vh, MK, 384, 384, 384);
    attn_kernel<<<B_ * H_, 256, 0, stream>>>(qh, kh, vh, ctx);
    g64(stream, 0, ctx, E_, w_o, bo, residual, residual, M, 384, 384, 384, 384);

    layernorm_kernel<<<M / 4, 256, 0, stream>>>(residual, ln1_w, ln1_b, hidden);
    g128(stream, 1, 1, hidden, E_, w_f1, ffn_b1, nullptr, ffnb, M, 1536, 384, 1536);
    g64(stream, 0, ffnb, HID_, w_f2, ffn_b2, residual, residual, M, 384, 1536, 384, 384);
    layernorm_kernel<<<M / 4, 256, 0, stream>>>(residual, ln2_w, ln2_b, hidden);

    g64(stream, 0, hidden, E_, w_lg, out_b, nullptr, (float*)d_out, M, V_, 384, V_, V_);
}